// Round 6
// baseline (52.475 us; speedup 1.0000x reference)
//
#include <hip/hip_runtime.h>

// Keep IEEE mul-then-add semantics (match JAX/XLA fp32 reference; near-tie
// d0<d1 coset decisions are sensitive to contraction/reassociation).
#pragma clang fp contract(off)

#define TINY_EPS 1.1920928955078125e-07f  // np.finfo(float32).eps

typedef float f4 __attribute__((ext_vector_type(4)));

// D8 rounding stage. Returns f[], delta[], first-argmax k, parity, and the
// flip residual rflip = z_k - adj (== reference's t at j=k when parity odd).
// All indexing compile-time after unroll (no scratch).
struct Dn8 {
    float f[8];
    float d[8];   // |z - f| ; square bit-equals (z-f)^2
    float adj;    // flipped value at k
    float rflip;  // __fsub_rn(z_k, adj)
    int   k;
    bool  odd;
};

__device__ __forceinline__ Dn8 dn8(const float z[8]) {
    Dn8 r;
    float fsum = 0.0f;
#pragma unroll
    for (int j = 0; j < 8; ++j) {
        float x  = z[j];
        float t  = x - __builtin_copysignf(TINY_EPS, x);  // == sign(x)*eps path
        float fv = floorf(t + 0.5f);                      // custom_round
        r.f[j] = fv;
        r.d[j] = fabsf(x - fv);
        fsum   = __fadd_rn(fsum, fv);  // exact: small integers (any order exact)
    }
    // first-max argmax; carry z[k], f[k] to avoid runtime indexing
    int   k  = 0;
    float bd = r.d[0], xk = z[0], fk = r.f[0];
#pragma unroll
    for (int j = 1; j < 8; ++j) {
        bool better = r.d[j] > bd;  // strict: first max wins (jnp.argmax)
        bd = better ? r.d[j] : bd;
        xk = better ? z[j] : xk;
        fk = better ? r.f[j] : fk;
        k  = better ? j : k;
    }
    bool  up  = (xk >= 0.0f) ? (fk < xk) : (fk <= xk);
    float adj = fk + (up ? 1.0f : -1.0f);
    r.adj   = adj;
    r.rflip = __fsub_rn(xk, adj);
    r.k     = k;
    r.odd   = (((int)fsum) & 1) != 0;  // exact int; C & matches jnp.mod parity
    return r;
}

// One E8 point: z[8] -> q[8] (scaled by beta). Bit-exact vs reference:
// d1 terms use (z-0.5)-fB which bit-equals z-(fB+0.5); +0.5 folded into
// epilogue via c (exact adds of half-integers).
__device__ __forceinline__ void e8_point(const float z[8], float beta, float q[8]) {
    float zs[8];
#pragma unroll
    for (int j = 0; j < 8; ++j) zs[j] = z[j] - 0.5f;  // exact in range

    Dn8 A = dn8(z);
    Dn8 B = dn8(zs);

    // squared distances in reference's sequential j order (no reassociation)
    float d0 = 0.0f, d1 = 0.0f;
#pragma unroll
    for (int j = 0; j < 8; ++j) {
        bool  mA = A.odd && (j == A.k);
        bool  mB = B.odd && (j == B.k);
        float vA = mA ? A.rflip : A.d[j];
        float vB = mB ? B.rflip : B.d[j];
        d0 = __fadd_rn(d0, __fmul_rn(vA, vA));
        d1 = __fadd_rn(d1, __fmul_rn(vB, vB));
    }
    bool  pick0 = d0 < d1;  // ties -> y1, matching jnp.where(d0 < d1, y0, y1)
    float c     = pick0 ? 0.0f : 0.5f;
#pragma unroll
    for (int j = 0; j < 8; ++j) {
        bool  mA = A.odd && (j == A.k);
        bool  mB = B.odd && (j == B.k);
        float yA = mA ? A.adj : A.f[j];
        float yB = mB ? B.adj : B.f[j];
        float w  = pick0 ? yA : yB;
        q[j] = __fmul_rn(beta, __fadd_rn(w, c));
    }
}

// 2 points per thread, fully branchless compute: both dependency chains live
// in one basic block so the scheduler interleaves them (2x ILP per wave).
// R4's version failed from bundled IEEE divides + branch-hidden B loads.
__global__ void __launch_bounds__(256, 4)
e8_quant_kernel(const float* __restrict__ x, const float* __restrict__ beta_p,
                const float* __restrict__ eps, float* __restrict__ out, int N) {
    int i  = blockIdx.x * blockDim.x + threadIdx.x;  // pair index
    int p0 = i * 2;
    if (p0 >= N) return;
    bool w2  = (p0 + 1) < N;
    int  p1c = w2 ? (p0 + 1) : p0;  // clamped load index (branchless)

    float beta = *beta_p;
    float e[8];
#pragma unroll
    for (int j = 0; j < 8; ++j) e[j] = eps[j];  // uniform -> scalar loads

    const f4* xp = reinterpret_cast<const f4*>(x);
    f4 a0 = xp[(size_t)p0 * 2 + 0];
    f4 a1 = xp[(size_t)p0 * 2 + 1];
    f4 b0 = xp[(size_t)p1c * 2 + 0];
    f4 b1 = xp[(size_t)p1c * 2 + 1];

    float zA[8] = {a0.x, a0.y, a0.z, a0.w, a1.x, a1.y, a1.z, a1.w};
    float zB[8] = {b0.x, b0.y, b0.z, b0.w, b1.x, b1.y, b1.z, b1.w};

    if (beta == 1.0f) {  // uniform branch; bit-exact: x/1.0 == x
#pragma unroll
        for (int j = 0; j < 8; ++j) { zA[j] = zA[j] + e[j]; zB[j] = zB[j] + e[j]; }
    } else {
#pragma unroll
        for (int j = 0; j < 8; ++j) { zA[j] = zA[j] / beta + e[j]; zB[j] = zB[j] / beta + e[j]; }
    }

    float qA[8], qB[8];
    e8_point(zA, beta, qA);
    e8_point(zB, beta, qB);

    f4* op = reinterpret_cast<f4*>(out);
    f4 sA0 = {qA[0], qA[1], qA[2], qA[3]};
    f4 sA1 = {qA[4], qA[5], qA[6], qA[7]};
    op[(size_t)p0 * 2 + 0] = sA0;
    op[(size_t)p0 * 2 + 1] = sA1;
    if (w2) {
        f4 sB0 = {qB[0], qB[1], qB[2], qB[3]};
        f4 sB1 = {qB[4], qB[5], qB[6], qB[7]};
        op[(size_t)(p0 + 1) * 2 + 0] = sB0;
        op[(size_t)(p0 + 1) * 2 + 1] = sB1;
    }
}

extern "C" void kernel_launch(void* const* d_in, const int* in_sizes, int n_in,
                              void* d_out, int out_size, void* d_ws, size_t ws_size,
                              hipStream_t stream) {
    const float* x      = (const float*)d_in[0];
    const float* beta_p = (const float*)d_in[1];
    const float* eps    = (const float*)d_in[2];
    float*       out    = (float*)d_out;

    int N     = in_sizes[0] / 8;   // 4,000,000 points
    int pairs = (N + 1) / 2;       // 2 points per thread
    int block = 256;
    int grid  = (pairs + block - 1) / block;
    hipLaunchKernelGGL(e8_quant_kernel, dim3(grid), dim3(block), 0, stream,
                       x, beta_p, eps, out, N);
}

// Round 7
// 41.561 us; speedup vs baseline: 1.2626x; 1.2626x over previous
//
#include <hip/hip_runtime.h>

// Keep IEEE mul-then-add semantics (match JAX/XLA fp32 reference; near-tie
// d0<d1 coset decisions are sensitive to contraction/reassociation).
#pragma clang fp contract(off)

#define TINY_EPS 1.1920928955078125e-07f  // np.finfo(float32).eps

typedef float f4 __attribute__((ext_vector_type(4)));

// D8 rounding stage. Returns f[], delta[], first-argmax k, parity, and the
// flip residual rflip = z_k - adj. All indexing compile-time (no scratch).
struct Dn8 {
    float f[8];
    float d[8];   // |z - f| ; square bit-equals (z-f)^2
    float adj;    // flipped value at k
    float rflip;  // __fsub_rn(z_k, adj)
    int   k;
    bool  odd;
};

__device__ __forceinline__ Dn8 dn8(const float z[8]) {
    Dn8 r;
    float fsum = 0.0f;
#pragma unroll
    for (int j = 0; j < 8; ++j) {
        float x  = z[j];
        float t  = x - __builtin_copysignf(TINY_EPS, x);  // == sign(x)*eps path
        float fv = floorf(t + 0.5f);                      // custom_round
        r.f[j] = fv;
        r.d[j] = fabsf(x - fv);
        fsum   = __fadd_rn(fsum, fv);  // exact: small integers
    }
    // first-max argmax; carry z[k], f[k] to avoid runtime indexing
    int   k  = 0;
    float bd = r.d[0], xk = z[0], fk = r.f[0];
#pragma unroll
    for (int j = 1; j < 8; ++j) {
        bool better = r.d[j] > bd;  // strict: first max wins (jnp.argmax)
        bd = better ? r.d[j] : bd;
        xk = better ? z[j] : xk;
        fk = better ? r.f[j] : fk;
        k  = better ? j : k;
    }
    bool  up  = (xk >= 0.0f) ? (fk < xk) : (fk <= xk);
    float adj = fk + (up ? 1.0f : -1.0f);
    r.adj   = adj;
    r.rflip = __fsub_rn(xk, adj);
    r.k     = k;
    r.odd   = (((int)fsum) & 1) != 0;
    return r;
}

// One E8 point: z[8] -> q[8] (scaled by beta). Bit-exact vs reference:
// d1 terms use (z-0.5)-fB which bit-equals z-(fB+0.5); +0.5 folded into
// epilogue via c (exact adds of half-integers).
__device__ __forceinline__ void e8_point(const float z[8], float beta, float q[8]) {
    float zs[8];
#pragma unroll
    for (int j = 0; j < 8; ++j) zs[j] = z[j] - 0.5f;

    Dn8 A = dn8(z);
    Dn8 B = dn8(zs);

    // squared distances in reference's sequential j order (no reassociation)
    float d0 = 0.0f, d1 = 0.0f;
#pragma unroll
    for (int j = 0; j < 8; ++j) {
        bool  mA = A.odd && (j == A.k);
        bool  mB = B.odd && (j == B.k);
        float vA = mA ? A.rflip : A.d[j];
        float vB = mB ? B.rflip : B.d[j];
        d0 = __fadd_rn(d0, __fmul_rn(vA, vA));
        d1 = __fadd_rn(d1, __fmul_rn(vB, vB));
    }
    bool  pick0 = d0 < d1;  // ties -> y1, matching jnp.where(d0 < d1, y0, y1)
    float c     = pick0 ? 0.0f : 0.5f;
#pragma unroll
    for (int j = 0; j < 8; ++j) {
        bool  mA = A.odd && (j == A.k);
        bool  mB = B.odd && (j == B.k);
        float yA = mA ? A.adj : A.f[j];
        float yB = mB ? B.adj : B.f[j];
        float w  = pick0 ? yA : yB;
        q[j] = __fmul_rn(beta, __fadd_rn(w, c));
    }
}

// 1 point per thread (best measured structure). Store path: transpose via LDS
// so each global_store_dwordx4 is lane-contiguous (full 128B lines), then
// NONTEMPORAL store -> output bypasses L3 -> 128MB input stays L3-resident
// across replays (FETCH drops), and full-line nt writes don't amplify
// (R3's 1.63x amp came from stride-32B partial-line nt stores).
__global__ void __launch_bounds__(256)
e8_quant_kernel(const float* __restrict__ x, const float* __restrict__ beta_p,
                const float* __restrict__ eps, float* __restrict__ out, int N) {
    __shared__ float tile[8][257];  // SoA, +1 pad: writes conflict-free,
                                    // reads 2-way (free per m136)
    int tid = threadIdx.x;
    int i   = blockIdx.x * 256 + tid;
    bool full_block = ((blockIdx.x + 1) * 256) <= N;  // block-uniform
    if (!full_block && i >= N) return;                // no barrier on this path

    float beta = *beta_p;
    float e[8];
#pragma unroll
    for (int j = 0; j < 8; ++j) e[j] = eps[j];  // uniform -> scalar loads

    const f4* xp = reinterpret_cast<const f4*>(x) + (size_t)i * 2;
    f4 a = xp[0];
    f4 b = xp[1];
    float z[8] = {a.x, a.y, a.z, a.w, b.x, b.y, b.z, b.w};

    if (beta == 1.0f) {  // uniform branch; bit-exact: x/1.0 == x
#pragma unroll
        for (int j = 0; j < 8; ++j) z[j] = z[j] + e[j];
    } else {
#pragma unroll
        for (int j = 0; j < 8; ++j) z[j] = z[j] / beta + e[j];  // IEEE div
    }

    float q[8];
    e8_point(z, beta, q);

    if (full_block) {
        // stage own point: column = tid, conflict-free (257 stride)
#pragma unroll
        for (int j = 0; j < 8; ++j) tile[j][tid] = q[j];
        __syncthreads();
        // lane-contiguous nt stores: wave covers its own 64 points = 2KB
        int wave = tid >> 6, lane = tid & 63;
        int wb   = wave << 6;
        f4* op   = reinterpret_cast<f4*>(out) + (size_t)blockIdx.x * 512 + wave * 128;
#pragma unroll
        for (int c = 0; c < 2; ++c) {
            int p = wb + c * 32 + (lane >> 1);  // source point (block-local tid)
            int h = (lane & 1) << 2;            // which half: q[0..3] or q[4..7]
            f4 v = {tile[h + 0][p], tile[h + 1][p], tile[h + 2][p], tile[h + 3][p]};
            __builtin_nontemporal_store(v, op + c * 64 + lane);
        }
    } else {
        // tail fallback (never taken at N=4e6=15625*256): plain cached stores
        f4* op = reinterpret_cast<f4*>(out) + (size_t)i * 2;
        f4 s0 = {q[0], q[1], q[2], q[3]};
        f4 s1 = {q[4], q[5], q[6], q[7]};
        op[0] = s0;
        op[1] = s1;
    }
}

extern "C" void kernel_launch(void* const* d_in, const int* in_sizes, int n_in,
                              void* d_out, int out_size, void* d_ws, size_t ws_size,
                              hipStream_t stream) {
    const float* x      = (const float*)d_in[0];
    const float* beta_p = (const float*)d_in[1];
    const float* eps    = (const float*)d_in[2];
    float*       out    = (float*)d_out;

    int N     = in_sizes[0] / 8;  // 4,000,000 points
    int block = 256;
    int grid  = (N + block - 1) / block;
    hipLaunchKernelGGL(e8_quant_kernel, dim3(grid), dim3(block), 0, stream,
                       x, beta_p, eps, out, N);
}